// Round 3
// baseline (1177.462 us; speedup 1.0000x reference)
//
#include <hip/hip_runtime.h>
#include <hip/hip_fp16.h>

#define D 128
#define DP 132  // LDS row stride (floats): +4 pad; Phase-B row stride 2*DP
                // lands 2-way per bank (free, m136); rows stay 16B-aligned.
#define TM 16   // fused layer tile: 16 nodes, ~16.5 KB LDS -> 8 blocks/CU

typedef float f4v __attribute__((ext_vector_type(4)));

// ---------------- CSR build ----------------

__global__ void hist_kernel(const int* __restrict__ dst, int* __restrict__ deg, int E) {
    int i = blockIdx.x * blockDim.x + threadIdx.x;
    if (i < E) atomicAdd(&deg[dst[i]], 1);
}

__global__ void scan1_kernel(const int* __restrict__ deg, int* __restrict__ local_excl,
                             int* __restrict__ blocksum, int n) {
    __shared__ int tmp[1024];
    int i = blockIdx.x * 1024 + threadIdx.x;
    int v = (i < n) ? deg[i] : 0;
    tmp[threadIdx.x] = v;
    __syncthreads();
    for (int off = 1; off < 1024; off <<= 1) {
        int t = 0;
        if (threadIdx.x >= off) t = tmp[threadIdx.x - off];
        __syncthreads();
        if (threadIdx.x >= off) tmp[threadIdx.x] += t;
        __syncthreads();
    }
    int incl = tmp[threadIdx.x];
    if (i < n) local_excl[i] = incl - v;
    if (threadIdx.x == 1023) blocksum[blockIdx.x] = tmp[1023];
}

__global__ void scan2_kernel(int* __restrict__ blocksum, int nb) {
    __shared__ int tmp[1024];
    int v = (threadIdx.x < nb) ? blocksum[threadIdx.x] : 0;
    tmp[threadIdx.x] = v;
    __syncthreads();
    for (int off = 1; off < 1024; off <<= 1) {
        int t = 0;
        if (threadIdx.x >= off) t = tmp[threadIdx.x - off];
        __syncthreads();
        if (threadIdx.x >= off) tmp[threadIdx.x] += t;
        __syncthreads();
    }
    if (threadIdx.x < nb) blocksum[threadIdx.x] = tmp[threadIdx.x] - v;  // exclusive
}

__global__ void scan3_kernel(const int* __restrict__ deg, const int* __restrict__ local_excl,
                             const int* __restrict__ blocksum, int* __restrict__ row_start,
                             int* __restrict__ cursor, float* __restrict__ inv_deg,
                             int n, int n_edges) {
    int i = blockIdx.x * 1024 + threadIdx.x;
    if (i < n) {
        int rs = local_excl[i] + blocksum[blockIdx.x];
        row_start[i] = rs;
        cursor[i]    = rs;
        inv_deg[i]   = 1.0f / fmaxf((float)deg[i], 1.0f);
    }
    if (i == 0) row_start[n] = n_edges;
}

// csr[] holds BYTE offsets of the fp16 source row (src * D * 2 = src * 256).
__global__ void scatter_kernel(const int* __restrict__ src, const int* __restrict__ dst,
                               int* __restrict__ cursor, int* __restrict__ csr, int E) {
    int i = blockIdx.x * blockDim.x + threadIdx.x;
    if (i < E) {
        int d = dst[i];
        int p = atomicAdd(&cursor[d], 1);
        csr[p] = src[i] << 8;   // * 256 bytes per fp16 row
    }
}

// ---------------- weight transpose (W[l][f][k] -> Wt[l][k][f]) ----------------

__global__ void transpose_w(const float* __restrict__ Wl, const float* __restrict__ Wr,
                            float* __restrict__ Wlt, float* __restrict__ Wrt, int total) {
    int i = blockIdx.x * blockDim.x + threadIdx.x;
    if (i < total) {
        int l = i >> 14;
        int r = i & 16383;
        int f = r >> 7;
        int k = r & 127;
        int o = (l << 14) + (k << 7) + f;
        Wlt[o] = Wl[i];
        Wrt[o] = Wr[i];
    }
}

// ---------------- initial fp32 -> fp16 shadow copy ----------------

__global__ void x_to_half(const float* __restrict__ x, __half* __restrict__ xh, int total4) {
    int i = blockIdx.x * blockDim.x + threadIdx.x;   // one float4 per thread
    if (i < total4) {
        float4 v = ((const float4*)x)[i];
        __half2 h0 = __float22half2_rn(make_float2(v.x, v.y));
        __half2 h1 = __float22half2_rn(make_float2(v.z, v.w));
        uint2 u;
        u.x = *(unsigned int*)&h0;
        u.y = *(unsigned int*)&h1;
        ((uint2*)xh)[i] = u;
    }
}

// ---------------- fused SAGE layer ----------------
// Phase A (r12 change): one 16-lane group per node -> all 16 nodes of the
// tile gather CONCURRENTLY (r11 post-mortem: only ~27 lines in flight/CU
// because one wave owned 4 nodes sequentially with a ~2000cy drain chain
// per node). A group covers a full 256B fp16 row per dwordx4 load; 4-deep
// edge pipeline + software-prefetched csr indices for the next window.
// Accumulation is lane-local: NO shfl reduction (kills the 400K bank
// conflicts), group writes its A-row directly. Per-wave in-flight loads
// 4 -> 16.
// nt hints: the fp32 streams (X-tile reads, xout writes; ~102 MB/layer)
// are marked non-temporal so they stop evicting the 25.6 MB fp16 gather
// working set from Infinity Cache. xh writes stay cached (next layer's
// gather source).
// Phase B: feature-sliced waves (r10), fp32 GEMM from LDS, unchanged.
#define FMA4(ACC, W, S) ACC.x += W.x * (S); ACC.y += W.y * (S); \
                        ACC.z += W.z * (S); ACC.w += W.w * (S);

// Accumulate 8 fp16 features (one dwordx4) into sA/sB fp32 accumulators.
#define ACC8(V) { const __half2* hp_ = (const __half2*)&(V);                 \
    float2 f0_ = __half22float2(hp_[0]); float2 f1_ = __half22float2(hp_[1]);\
    float2 f2_ = __half22float2(hp_[2]); float2 f3_ = __half22float2(hp_[3]);\
    sA.x += f0_.x; sA.y += f0_.y; sA.z += f1_.x; sA.w += f1_.y;              \
    sB.x += f2_.x; sB.y += f2_.y; sB.z += f3_.x; sB.w += f3_.y; }

__global__ void sage_layer(const float* __restrict__ xin,
                           const __half* __restrict__ xh_in,
                           float* __restrict__ xout,
                           __half* __restrict__ xh_out,
                           const int* __restrict__ row_start, const int* __restrict__ csr,
                           const float* __restrict__ inv_deg,
                           const float* __restrict__ Wlt, const float* __restrict__ Wrt,
                           const float* __restrict__ bl, int n_nodes) {
    __shared__ __align__(16) float A[TM][DP];
    __shared__ __align__(16) float X[TM][DP];
    int block0 = blockIdx.x * TM;
    int tid = threadIdx.x;

    // X-tile fill: 512 float4s, 2 per thread, nt loads (stream, read once).
    {
        for (int idx = tid; idx < TM * 32; idx += 256) {
            int row = idx >> 5, c4 = idx & 31;
            int nn = block0 + row;
            f4v v = {0.f, 0.f, 0.f, 0.f};
            if (nn < n_nodes)
                v = __builtin_nontemporal_load((const f4v*)(xin + (size_t)nn * D) + c4);
            *((f4v*)X[row] + c4) = v;
        }
    }

    // Phase A: group g (16 lanes) owns node block0+g.
    {
        int g   = tid >> 4;       // 0..15
        int sub = tid & 15;
        int n = block0 + g;
        const char* hbase = (const char*)xh_in;
        int laneoff = sub * 16;   // 16B per lane within 256B row
        float4 sA = {0,0,0,0}, sB = {0,0,0,0};
        float idg = 1.f;
        int e0 = 0, e1 = 0;
        if (n < n_nodes) {
            e0 = row_start[n];
            e1 = row_start[n + 1];
            idg = inv_deg[n];
        }
        int e = e0;
        if (e < e1) {
            int last = e1 - 1;
            int i0 = csr[min(e,     last)];
            int i1 = csr[min(e + 1, last)];
            int i2 = csr[min(e + 2, last)];
            int i3 = csr[min(e + 3, last)];
            while (1) {
                float4 v0 = *(const float4*)(hbase + (size_t)(i0 + laneoff));
                float4 v1 = *(const float4*)(hbase + (size_t)(i1 + laneoff));
                float4 v2 = *(const float4*)(hbase + (size_t)(i2 + laneoff));
                float4 v3 = *(const float4*)(hbase + (size_t)(i3 + laneoff));
                int en = e + 4;
                bool more = en < e1;
                int p0, p1, p2, p3;
                if (more) {   // prefetch next window's indices under the gathers
                    p0 = csr[min(en,     last)];
                    p1 = csr[min(en + 1, last)];
                    p2 = csr[min(en + 2, last)];
                    p3 = csr[min(en + 3, last)];
                }
                ACC8(v0)
                if (e + 1 <= last) ACC8(v1)
                if (e + 2 <= last) ACC8(v2)
                if (e + 3 <= last) ACC8(v3)
                if (!more) break;
                e = en;
                i0 = p0; i1 = p1; i2 = p2; i3 = p3;
            }
        }
        sA.x *= idg; sA.y *= idg; sA.z *= idg; sA.w *= idg;
        sB.x *= idg; sB.y *= idg; sB.z *= idg; sB.w *= idg;
        ((float4*)A[g])[sub * 2]     = sA;
        ((float4*)A[g])[sub * 2 + 1] = sB;
    }
    __syncthreads();

    // Phase B: wave w owns feature float4-columns [w*8, w*8+8) for all 16
    // nodes. Thread = 8 features x 2 nodes, k-step 4, chained fmacs.
    {
        int lane = tid & 63;
        int w    = tid >> 6;
        int c8   = lane & 7;        // float4 col within wave slice
        int tn   = lane >> 3;       // 0..7
        int cols4 = w * 8 + c8;     // global float4 col 0..31
        int j0 = tn * 2, j1 = j0 + 1;
        const float4* wlp = (const float4*)Wlt + cols4;   // row k at wlp[k*32]
        const float4* wrp = (const float4*)Wrt + cols4;
        float4 bv = ((const float4*)bl)[cols4];
        float4 acc0 = bv, acc1 = bv;
        const float* Arow0 = A[j0];
        const float* Arow1 = A[j1];
        const float* Xrow0 = X[j0];
        const float* Xrow1 = X[j1];

        for (int k = 0; k < D; k += 4) {
            float4 wl0 = wlp[(k + 0) * 32];
            float4 wl1 = wlp[(k + 1) * 32];
            float4 wl2 = wlp[(k + 2) * 32];
            float4 wl3 = wlp[(k + 3) * 32];
            float4 wr0 = wrp[(k + 0) * 32];
            float4 wr1 = wrp[(k + 1) * 32];
            float4 wr2 = wrp[(k + 2) * 32];
            float4 wr3 = wrp[(k + 3) * 32];
            float4 a0 = *(const float4*)&Arow0[k];
            float4 a1 = *(const float4*)&Arow1[k];
            float4 x0 = *(const float4*)&Xrow0[k];
            float4 x1 = *(const float4*)&Xrow1[k];

            FMA4(acc0, wl0, a0.x) FMA4(acc0, wl1, a0.y)
            FMA4(acc0, wl2, a0.z) FMA4(acc0, wl3, a0.w)
            FMA4(acc0, wr0, x0.x) FMA4(acc0, wr1, x0.y)
            FMA4(acc0, wr2, x0.z) FMA4(acc0, wr3, x0.w)
            FMA4(acc1, wl0, a1.x) FMA4(acc1, wl1, a1.y)
            FMA4(acc1, wl2, a1.z) FMA4(acc1, wl3, a1.w)
            FMA4(acc1, wr0, x1.x) FMA4(acc1, wr1, x1.y)
            FMA4(acc1, wr2, x1.z) FMA4(acc1, wr3, x1.w)
        }

        int n0 = block0 + j0, n1 = block0 + j1;
        if (n0 < n_nodes) {
            f4v r;
            r.x = fmaxf(acc0.x, 0.f); r.y = fmaxf(acc0.y, 0.f);
            r.z = fmaxf(acc0.z, 0.f); r.w = fmaxf(acc0.w, 0.f);
            __builtin_nontemporal_store(r, (f4v*)xout + (size_t)n0 * 32 + cols4);
            __half2 h0 = __float22half2_rn(make_float2(r.x, r.y));
            __half2 h1 = __float22half2_rn(make_float2(r.z, r.w));
            uint2 u;
            u.x = *(unsigned int*)&h0;
            u.y = *(unsigned int*)&h1;
            ((uint2*)xh_out)[(size_t)n0 * 32 + cols4] = u;
        }
        if (n1 < n_nodes) {
            f4v r;
            r.x = fmaxf(acc1.x, 0.f); r.y = fmaxf(acc1.y, 0.f);
            r.z = fmaxf(acc1.z, 0.f); r.w = fmaxf(acc1.w, 0.f);
            __builtin_nontemporal_store(r, (f4v*)xout + (size_t)n1 * 32 + cols4);
            __half2 h0 = __float22half2_rn(make_float2(r.x, r.y));
            __half2 h1 = __float22half2_rn(make_float2(r.z, r.w));
            uint2 u;
            u.x = *(unsigned int*)&h0;
            u.y = *(unsigned int*)&h1;
            ((uint2*)xh_out)[(size_t)n1 * 32 + cols4] = u;
        }
    }
}

extern "C" void kernel_launch(void* const* d_in, const int* in_sizes, int n_in,
                              void* d_out, int out_size, void* d_ws, size_t ws_size,
                              hipStream_t stream) {
    const float* x  = (const float*)d_in[0];
    const int*  edge = (const int*)d_in[1];
    const float* Wl = (const float*)d_in[2];
    const float* bl = (const float*)d_in[3];
    const float* Wr = (const float*)d_in[4];

    int N = in_sizes[0] / D;
    int E = in_sizes[1] / 2;
    int L = in_sizes[3] / D;
    const int* srcp = edge;
    const int* dstp = edge + E;

    char* w = (char*)d_ws;
    auto alloc = [&](size_t bytes) {
        char* p = w;
        w += (bytes + 255) & ~(size_t)255;
        return p;
    };
    int*   deg       = (int*)alloc((size_t)N * 4);
    int*   local_ex  = (int*)alloc((size_t)N * 4);
    int*   row_start = (int*)alloc((size_t)(N + 1) * 4);
    int*   cursor    = (int*)alloc((size_t)N * 4);
    int*   csr       = (int*)alloc((size_t)E * 4);
    float* invdeg    = (float*)alloc((size_t)N * 4);
    int*   blocksum  = (int*)alloc((size_t)1024 * 4);
    float* wlt       = (float*)alloc((size_t)L * D * D * 4);
    float* wrt       = (float*)alloc((size_t)L * D * D * 4);
    float* buf0      = (float*)alloc((size_t)N * D * 4);
    __half* xh0      = (__half*)alloc((size_t)N * D * 2);
    __half* xh1      = (__half*)alloc((size_t)N * D * 2);

    int nb1 = (N + 1023) / 1024;
    hipMemsetAsync(deg, 0, (size_t)N * 4, stream);
    hist_kernel<<<(E + 255) / 256, 256, 0, stream>>>(dstp, deg, E);
    scan1_kernel<<<nb1, 1024, 0, stream>>>(deg, local_ex, blocksum, N);
    scan2_kernel<<<1, 1024, 0, stream>>>(blocksum, nb1);
    scan3_kernel<<<nb1, 1024, 0, stream>>>(deg, local_ex, blocksum, row_start,
                                           cursor, invdeg, N, E);
    scatter_kernel<<<(E + 255) / 256, 256, 0, stream>>>(srcp, dstp, cursor, csr, E);
    int tw = L * D * D;
    transpose_w<<<(tw + 255) / 256, 256, 0, stream>>>(Wl, Wr, wlt, wrt, tw);
    int t4 = N * (D / 4);
    x_to_half<<<(t4 + 255) / 256, 256, 0, stream>>>(x, xh0, t4);

    float* out = (float*)d_out;
    const float* cur = x;
    int nbl = (N + TM - 1) / TM;
    for (int l = 0; l < L; ++l) {
        float* o = (l & 1) ? out : buf0;
        if (l == L - 1) o = out;
        __half* hin  = (l & 1) ? xh1 : xh0;
        __half* hout = (l & 1) ? xh0 : xh1;
        sage_layer<<<nbl, 256, 0, stream>>>(cur, hin, o, hout, row_start, csr, invdeg,
                                            wlt + (size_t)l * D * D,
                                            wrt + (size_t)l * D * D,
                                            bl + (size_t)l * D, N);
        cur = o;
    }
}